// Round 4
// baseline (114.386 us; speedup 1.0000x reference)
//
#include <hip/hip_runtime.h>

// Problem constants
#define B_  16
#define T_  256
#define K_  128
#define DK_ 256
#define U_  128
#define TT_ 4      // timesteps per attn block (grid 1024 -> 4 blocks/CU)

#define SCALE_ 2.8853900817779268f  // 2*log2(e): exp(2x) = exp2(SCALE_*x)

// Static device scratch. Both hold SCALE_*(X@W + b):
// g_E2[m][u],  m in [0, B*T);  g_Km2[n][u], n in [0, B*K)
__device__ float g_E2[B_ * T_ * U_];
__device__ float g_Km2[B_ * K_ * U_];

// ---------------------------------------------------------------------------
// Fused GEMMs, 8 rows/block: blocks [0,512) -> E rows, [512,768) -> Km rows.
// 768 blocks = 3 blocks/CU (vs 1.5 at 16 rows/block): shorter serial prefix.
// ---------------------------------------------------------------------------
__global__ __launch_bounds__(256) void gemm_both(const float* __restrict__ enc,
                                                 const float* __restrict__ W1,
                                                 const float* __restrict__ b1,
                                                 const float* __restrict__ knw,
                                                 const float* __restrict__ W2,
                                                 const float* __restrict__ b2) {
    __shared__ float Xs[8][256];   // 8 KB

    const int blk  = blockIdx.x;
    const bool isE = blk < 512;
    const float* __restrict__ X    = isE ? enc : knw;
    const float* __restrict__ W    = isE ? W1 : W2;
    const float* __restrict__ bias = isE ? b1 : b2;
    float* __restrict__ Y          = isE ? g_E2 : g_Km2;
    const int row0 = (isE ? blk : blk - 512) * 8;
    const int tid  = threadIdx.x;

    // Stage 8 rows x 256 floats = 512 float4, 2 per thread, coalesced.
#pragma unroll
    for (int j = 0; j < 2; j++) {
        const int i  = tid + j * 256;
        const int rr = i >> 6, cc = i & 63;
        *(float4*)&Xs[rr][cc * 4] =
            *(const float4*)&X[(row0 + rr) * 256 + cc * 4];
    }
    __syncthreads();

    const int uc = tid & 31;       // u4 = 4*uc
    const int r  = tid >> 5;       // row 0..7
    float4 acc = {0.f, 0.f, 0.f, 0.f};

    for (int d = 0; d < 256; d += 4) {
        const float4 x4 = *(const float4*)&Xs[r][d];       // broadcast
        const float* wp = &W[d * 128 + uc * 4];
        const float4 w0 = *(const float4*)(wp);
        const float4 w1 = *(const float4*)(wp + 128);
        const float4 w2 = *(const float4*)(wp + 256);
        const float4 w3 = *(const float4*)(wp + 384);
        acc.x = fmaf(x4.x, w0.x, acc.x); acc.y = fmaf(x4.x, w0.y, acc.y);
        acc.z = fmaf(x4.x, w0.z, acc.z); acc.w = fmaf(x4.x, w0.w, acc.w);
        acc.x = fmaf(x4.y, w1.x, acc.x); acc.y = fmaf(x4.y, w1.y, acc.y);
        acc.z = fmaf(x4.y, w1.z, acc.z); acc.w = fmaf(x4.y, w1.w, acc.w);
        acc.x = fmaf(x4.z, w2.x, acc.x); acc.y = fmaf(x4.z, w2.y, acc.y);
        acc.z = fmaf(x4.z, w2.z, acc.z); acc.w = fmaf(x4.z, w2.w, acc.w);
        acc.x = fmaf(x4.w, w3.x, acc.x); acc.y = fmaf(x4.w, w3.y, acc.y);
        acc.z = fmaf(x4.w, w3.z, acc.z); acc.w = fmaf(x4.w, w3.w, acc.w);
    }

    const float4 b4 = *(const float4*)&bias[uc * 4];
    float4 o;
    o.x = SCALE_ * (acc.x + b4.x);
    o.y = SCALE_ * (acc.y + b4.y);
    o.z = SCALE_ * (acc.z + b4.z);
    o.w = SCALE_ * (acc.w + b4.w);
    *(float4*)&Y[(row0 + r) * 128 + uc * 4] = o;
}

// ---------------------------------------------------------------------------
// Fused scores -> softmax -> context. One block per (b, tile of 4 t's).
// XCD-pinned: blocks are dispatched round-robin over 8 XCDs (xcd = blk % 8),
// so we derive b from blk%8 -> all 64 blocks of a given b land on one XCD
// and knw[b] (2.1 MB) + Km2[b] (64 KB) stay L2-resident (2 b's ~ 4.2 MB/XCD).
// score_k = const - sum_u 2V[u]/(1+exp2(E2+Km2)); consts cancel in softmax.
// ---------------------------------------------------------------------------
__global__ __launch_bounds__(256, 4) void attn_ctx(const float* __restrict__ knw,
                                                   const float* __restrict__ V,
                                                   float* __restrict__ out) {
    __shared__ float sm[4][TT_][256];   // 16 KB: phase1 pA/V2s, phase2 part2
    __shared__ float E2s[TT_][U_];      // 2 KB
    __shared__ float attn[TT_][K_];     // 2 KB
    float* const pA  = &sm[0][0][0];    // [TT_][256] score partials
    float* const V2s = &sm[1][0][0];    // 128 floats = 2*V

    const int tid  = threadIdx.x;
    const int blk  = blockIdx.x;
    // XCD-pinning swizzle: xcd = blk & 7, j = blk >> 3 in [0,128)
    const int xcd  = blk & 7;
    const int j    = blk >> 3;
    const int b    = xcd * 2 + (j >> 6);   // 2 b's per XCD
    const int t0   = (j & 63) * TT_;
    const int lane = tid & 63;
    const int wave = tid >> 6;

    if (tid < 128) V2s[tid] = 2.0f * V[tid];
    if (tid < 128) {                    // stage E2 rows (4 x 128)
        const int ti = tid >> 5, uc = tid & 31;
        *(float4*)&E2s[ti][uc * 4] =
            *(const float4*)&g_E2[(b * T_ + t0 + ti) * U_ + uc * 4];
    }

    // Thread owns (k, half-of-U): 64 Km2 values in VGPRs, reused over 4 t's.
    const int k_idx = tid & 127;
    const int half  = tid >> 7;
    float4 km[16];
    {
        const float* kp = &g_Km2[(b * K_ + k_idx) * U_ + half * 64];
#pragma unroll
        for (int c = 0; c < 16; c++) km[c] = *(const float4*)&kp[c * 4];
    }
    __syncthreads();

    // ---- Phase 1: na[t] = sum_{u in half} 2V[u]/(1+exp2(e'+k')) ----
    {
        float na[TT_] = {0.f, 0.f, 0.f, 0.f};
#pragma unroll
        for (int c = 0; c < 16; c++) {
            const float4 v4 = *(const float4*)&V2s[half * 64 + c * 4];
#pragma unroll
            for (int t = 0; t < TT_; t++) {
                const float4 e4 = *(const float4*)&E2s[t][half * 64 + c * 4];
                float x, r;
                x = e4.x + km[c].x;
                r = __builtin_amdgcn_rcpf(1.0f + __builtin_amdgcn_exp2f(x));
                na[t] = fmaf(v4.x, r, na[t]);
                x = e4.y + km[c].y;
                r = __builtin_amdgcn_rcpf(1.0f + __builtin_amdgcn_exp2f(x));
                na[t] = fmaf(v4.y, r, na[t]);
                x = e4.z + km[c].z;
                r = __builtin_amdgcn_rcpf(1.0f + __builtin_amdgcn_exp2f(x));
                na[t] = fmaf(v4.z, r, na[t]);
                x = e4.w + km[c].w;
                r = __builtin_amdgcn_rcpf(1.0f + __builtin_amdgcn_exp2f(x));
                na[t] = fmaf(v4.w, r, na[t]);
            }
        }
#pragma unroll
        for (int t = 0; t < TT_; t++) pA[t * 256 + tid] = na[t];
    }
    __syncthreads();

    // ---- Softmax over K=128: wave w owns timestep w ----
    {
        const int t = wave;
        const float* p = &pA[t * 256];
        float s0 = -(p[lane] + p[128 + lane]);
        float s1 = -(p[64 + lane] + p[192 + lane]);
        float m = fmaxf(s0, s1);
#pragma unroll
        for (int off = 32; off >= 1; off >>= 1)
            m = fmaxf(m, __shfl_xor(m, off));
        const float e0 = __builtin_amdgcn_exp2f(1.4426950408889634f * (s0 - m));
        const float e1 = __builtin_amdgcn_exp2f(1.4426950408889634f * (s1 - m));
        float ss = e0 + e1;
#pragma unroll
        for (int off = 32; off >= 1; off >>= 1)
            ss += __shfl_xor(ss, off);
        const float rinv = __builtin_amdgcn_rcpf(ss);
        attn[t][lane]      = e0 * rinv;
        attn[t][64 + lane] = e1 * rinv;
    }
    __syncthreads();

    // ---- Phase 2: context[ti][d] = sum_k attn[ti][k]*knw[b][k][d] ----
    // Wave kg covers k in [32kg, 32kg+32); lane covers d4 = 4*lane.
    {
        const int kg = wave, dq = lane;
        float4 acc[TT_];
#pragma unroll
        for (int ti = 0; ti < TT_; ti++) acc[ti] = make_float4(0.f, 0.f, 0.f, 0.f);

        const float* kp = &knw[(b * K_ + kg * 32) * DK_ + dq * 4];
#pragma unroll 4
        for (int ki = 0; ki < 32; ki++) {
            const float4 kn = *(const float4*)&kp[ki * DK_];
#pragma unroll
            for (int ti = 0; ti < TT_; ti++) {
                const float a = attn[ti][kg * 32 + ki];   // LDS broadcast
                acc[ti].x = fmaf(a, kn.x, acc[ti].x);
                acc[ti].y = fmaf(a, kn.y, acc[ti].y);
                acc[ti].z = fmaf(a, kn.z, acc[ti].z);
                acc[ti].w = fmaf(a, kn.w, acc[ti].w);
            }
        }
#pragma unroll
        for (int ti = 0; ti < TT_; ti++)
            *(float4*)&sm[kg][ti][dq * 4] = acc[ti];
    }
    __syncthreads();

    // Cross-wave K reduction + coalesced float4 store (4 rows x 256)
    {
        const int ti = tid >> 6, dd = tid & 63;
        const float4 s0 = *(const float4*)&sm[0][ti][dd * 4];
        const float4 s1 = *(const float4*)&sm[1][ti][dd * 4];
        const float4 s2 = *(const float4*)&sm[2][ti][dd * 4];
        const float4 s3 = *(const float4*)&sm[3][ti][dd * 4];
        float4 o;
        o.x = s0.x + s1.x + s2.x + s3.x;
        o.y = s0.y + s1.y + s2.y + s3.y;
        o.z = s0.z + s1.z + s2.z + s3.z;
        o.w = s0.w + s1.w + s2.w + s3.w;
        *(float4*)&out[(b * T_ + t0 + ti) * DK_ + dd * 4] = o;
    }
}

// ---------------------------------------------------------------------------
extern "C" void kernel_launch(void* const* d_in, const int* in_sizes, int n_in,
                              void* d_out, int out_size, void* d_ws,
                              size_t ws_size, hipStream_t stream) {
    (void)in_sizes; (void)n_in; (void)d_ws; (void)ws_size; (void)out_size;
    const float* knw = (const float*)d_in[0];  // [B,K,DK]
    const float* enc = (const float*)d_in[1];  // [B,T,DE]
    const float* W1  = (const float*)d_in[2];  // [DE,U]
    const float* b1  = (const float*)d_in[3];  // [U]
    const float* W2  = (const float*)d_in[4];  // [DK,U]
    const float* b2  = (const float*)d_in[5];  // [U]
    const float* V   = (const float*)d_in[6];  // [U,1]
    // d_in[7] = bV: constant over K, cancels in softmax -> unused.
    float* out = (float*)d_out;

    gemm_both<<<768, 256, 0, stream>>>(enc, W1, b1, knw, W2, b2);
    attn_ctx<<<B_ * (T_ / TT_), 256, 0, stream>>>(knw, V, out);
}

// Round 5
// 109.905 us; speedup vs baseline: 1.0408x; 1.0408x over previous
//
#include <hip/hip_runtime.h>

// Problem constants
#define B_  16
#define T_  256
#define K_  128
#define DK_ 256
#define U_  128
#define TT_ 4      // timesteps per attn block (grid = 16*64 = 1024 -> 4 blocks/CU)

#define SCALE_ 2.8853900817779268f  // 2*log2(e): exp(2x) = exp2(SCALE_*x)

// Static device scratch. Both hold SCALE_*(X@W + b):
// g_E2[m][u],  m in [0, B*T);  g_Km2[n][u], n in [0, B*K)
__device__ float g_E2[B_ * T_ * U_];
__device__ float g_Km2[B_ * K_ * U_];

// ---------------------------------------------------------------------------
// Fused GEMMs: blocks [0,256) -> E (4096 rows of enc@W1+b1),
//              blocks [256,384) -> Km (2048 rows of knw@W2+b2).
// 16 rows/block, 2 rows/thread: 32 fma per 4 global float4 loads.
// (R4's 8-row variant doubled W re-reads per output and regressed; 16 rows
//  is the measured sweet spot.)
// ---------------------------------------------------------------------------
__global__ __launch_bounds__(256) void gemm_both(const float* __restrict__ enc,
                                                 const float* __restrict__ W1,
                                                 const float* __restrict__ b1,
                                                 const float* __restrict__ knw,
                                                 const float* __restrict__ W2,
                                                 const float* __restrict__ b2) {
    __shared__ float Xs[16][256];   // 16 KB

    const int blk  = blockIdx.x;
    const bool isE = blk < 256;
    const float* __restrict__ X    = isE ? enc : knw;
    const float* __restrict__ W    = isE ? W1 : W2;
    const float* __restrict__ bias = isE ? b1 : b2;
    float* __restrict__ Y          = isE ? g_E2 : g_Km2;
    const int row0 = (isE ? blk : blk - 256) * 16;
    const int tid  = threadIdx.x;

    // Stage 16 rows x 256 floats = 1024 float4, 4 per thread, coalesced.
#pragma unroll
    for (int j = 0; j < 4; j++) {
        const int i  = tid + j * 256;
        const int rr = i >> 6, cc = i & 63;
        *(float4*)&Xs[rr][cc * 4] =
            *(const float4*)&X[(row0 + rr) * 256 + cc * 4];
    }
    __syncthreads();

    const int uc = tid & 31;          // u4 = 4*uc
    const int rp = (tid >> 5) * 2;    // rows rp, rp+1
    float4 a0 = {0.f, 0.f, 0.f, 0.f};
    float4 a1 = {0.f, 0.f, 0.f, 0.f};

    for (int d = 0; d < 256; d += 4) {
        const float4 xa = *(const float4*)&Xs[rp][d];       // broadcast
        const float4 xb = *(const float4*)&Xs[rp + 1][d];   // broadcast
        const float* wp = &W[d * 128 + uc * 4];
        const float4 w0 = *(const float4*)(wp);
        const float4 w1 = *(const float4*)(wp + 128);
        const float4 w2 = *(const float4*)(wp + 256);
        const float4 w3 = *(const float4*)(wp + 384);
        a0.x = fmaf(xa.x, w0.x, a0.x); a0.y = fmaf(xa.x, w0.y, a0.y);
        a0.z = fmaf(xa.x, w0.z, a0.z); a0.w = fmaf(xa.x, w0.w, a0.w);
        a0.x = fmaf(xa.y, w1.x, a0.x); a0.y = fmaf(xa.y, w1.y, a0.y);
        a0.z = fmaf(xa.y, w1.z, a0.z); a0.w = fmaf(xa.y, w1.w, a0.w);
        a0.x = fmaf(xa.z, w2.x, a0.x); a0.y = fmaf(xa.z, w2.y, a0.y);
        a0.z = fmaf(xa.z, w2.z, a0.z); a0.w = fmaf(xa.z, w2.w, a0.w);
        a0.x = fmaf(xa.w, w3.x, a0.x); a0.y = fmaf(xa.w, w3.y, a0.y);
        a0.z = fmaf(xa.w, w3.z, a0.z); a0.w = fmaf(xa.w, w3.w, a0.w);
        a1.x = fmaf(xb.x, w0.x, a1.x); a1.y = fmaf(xb.x, w0.y, a1.y);
        a1.z = fmaf(xb.x, w0.z, a1.z); a1.w = fmaf(xb.x, w0.w, a1.w);
        a1.x = fmaf(xb.y, w1.x, a1.x); a1.y = fmaf(xb.y, w1.y, a1.y);
        a1.z = fmaf(xb.y, w1.z, a1.z); a1.w = fmaf(xb.y, w1.w, a1.w);
        a1.x = fmaf(xb.z, w2.x, a1.x); a1.y = fmaf(xb.z, w2.y, a1.y);
        a1.z = fmaf(xb.z, w2.z, a1.z); a1.w = fmaf(xb.z, w2.w, a1.w);
        a1.x = fmaf(xb.w, w3.x, a1.x); a1.y = fmaf(xb.w, w3.y, a1.y);
        a1.z = fmaf(xb.w, w3.z, a1.z); a1.w = fmaf(xb.w, w3.w, a1.w);
    }

    const float4 b4 = *(const float4*)&bias[uc * 4];
    float4 o0, o1;
    o0.x = SCALE_ * (a0.x + b4.x); o0.y = SCALE_ * (a0.y + b4.y);
    o0.z = SCALE_ * (a0.z + b4.z); o0.w = SCALE_ * (a0.w + b4.w);
    o1.x = SCALE_ * (a1.x + b4.x); o1.y = SCALE_ * (a1.y + b4.y);
    o1.z = SCALE_ * (a1.z + b4.z); o1.w = SCALE_ * (a1.w + b4.w);
    *(float4*)&Y[(row0 + rp) * 128 + uc * 4]     = o0;
    *(float4*)&Y[(row0 + rp + 1) * 128 + uc * 4] = o1;
}

// ---------------------------------------------------------------------------
// Fused scores -> softmax -> context. One block per (b, tile of 4 t's).
// score_k = const - sum_u 2V[u]/(1+exp2(E2[t,u]+Km2[k,u])); consts cancel
// in softmax over K. Plain 5-instr sigmoid (R3's quad-rcp was neutral ->
// trans pipe is not the bottleneck; fewer issue slots wins). No XCD swizzle
// (R4's pinning regressed). 4 barriers; softmax parallel across 4 waves.
// ---------------------------------------------------------------------------
__global__ __launch_bounds__(256, 4) void attn_ctx(const float* __restrict__ knw,
                                                   const float* __restrict__ V,
                                                   float* __restrict__ out) {
    __shared__ float sm[4][TT_][256];   // 16 KB: phase1 pA/V2s, phase2 part2
    __shared__ float E2s[TT_][U_];      // 2 KB
    __shared__ float attn[TT_][K_];     // 2 KB
    float* const pA  = &sm[0][0][0];    // [TT_][256] score partials
    float* const V2s = &sm[1][0][0];    // 128 floats = 2*V

    const int tid  = threadIdx.x;
    const int blk  = blockIdx.x;
    const int b    = blk >> 6;          // 64 t-tiles per batch
    const int t0   = (blk & 63) * TT_;
    const int lane = tid & 63;
    const int wave = tid >> 6;

    if (tid < 128) V2s[tid] = 2.0f * V[tid];
    if (tid < 128) {                    // stage E2 rows (4 x 128)
        const int ti = tid >> 5, uc = tid & 31;
        *(float4*)&E2s[ti][uc * 4] =
            *(const float4*)&g_E2[(b * T_ + t0 + ti) * U_ + uc * 4];
    }

    // Thread owns (k, half-of-U): 64 Km2 values in VGPRs, reused over 4 t's.
    const int k_idx = tid & 127;
    const int half  = tid >> 7;
    float4 km[16];
    {
        const float* kp = &g_Km2[(b * K_ + k_idx) * U_ + half * 64];
#pragma unroll
        for (int c = 0; c < 16; c++) km[c] = *(const float4*)&kp[c * 4];
    }
    __syncthreads();

    // ---- Phase 1: na[t] = sum_{u in half} 2V[u]/(1+exp2(e'+k')) ----
    // All E2s/V2s reads are wave-uniform addresses -> LDS broadcast, free.
    {
        float na[TT_] = {0.f, 0.f, 0.f, 0.f};
#pragma unroll
        for (int c = 0; c < 16; c++) {
            const float4 v4 = *(const float4*)&V2s[half * 64 + c * 4];
#pragma unroll
            for (int t = 0; t < TT_; t++) {
                const float4 e4 = *(const float4*)&E2s[t][half * 64 + c * 4];
                float x, r;
                x = e4.x + km[c].x;
                r = __builtin_amdgcn_rcpf(1.0f + __builtin_amdgcn_exp2f(x));
                na[t] = fmaf(v4.x, r, na[t]);
                x = e4.y + km[c].y;
                r = __builtin_amdgcn_rcpf(1.0f + __builtin_amdgcn_exp2f(x));
                na[t] = fmaf(v4.y, r, na[t]);
                x = e4.z + km[c].z;
                r = __builtin_amdgcn_rcpf(1.0f + __builtin_amdgcn_exp2f(x));
                na[t] = fmaf(v4.z, r, na[t]);
                x = e4.w + km[c].w;
                r = __builtin_amdgcn_rcpf(1.0f + __builtin_amdgcn_exp2f(x));
                na[t] = fmaf(v4.w, r, na[t]);
            }
        }
#pragma unroll
        for (int t = 0; t < TT_; t++) pA[t * 256 + tid] = na[t];
    }
    __syncthreads();

    // ---- Softmax over K=128: wave w owns timestep w ----
    {
        const int t = wave;
        const float* p = &pA[t * 256];
        float s0 = -(p[lane] + p[128 + lane]);
        float s1 = -(p[64 + lane] + p[192 + lane]);
        float m = fmaxf(s0, s1);
#pragma unroll
        for (int off = 32; off >= 1; off >>= 1)
            m = fmaxf(m, __shfl_xor(m, off));
        const float e0 = __builtin_amdgcn_exp2f(1.4426950408889634f * (s0 - m));
        const float e1 = __builtin_amdgcn_exp2f(1.4426950408889634f * (s1 - m));
        float ss = e0 + e1;
#pragma unroll
        for (int off = 32; off >= 1; off >>= 1)
            ss += __shfl_xor(ss, off);
        const float rinv = __builtin_amdgcn_rcpf(ss);
        attn[t][lane]      = e0 * rinv;
        attn[t][64 + lane] = e1 * rinv;
    }
    __syncthreads();

    // ---- Phase 2: context[ti][d] = sum_k attn[ti][k]*knw[b][k][d] ----
    // Wave kg covers k in [32kg, 32kg+32); lane covers d4 = 4*lane.
    {
        const int kg = wave, dq = lane;
        float4 acc[TT_];
#pragma unroll
        for (int ti = 0; ti < TT_; ti++) acc[ti] = make_float4(0.f, 0.f, 0.f, 0.f);

        const float* kp = &knw[(b * K_ + kg * 32) * DK_ + dq * 4];
#pragma unroll 4
        for (int ki = 0; ki < 32; ki++) {
            const float4 kn = *(const float4*)&kp[ki * DK_];
#pragma unroll
            for (int ti = 0; ti < TT_; ti++) {
                const float a = attn[ti][kg * 32 + ki];   // LDS broadcast
                acc[ti].x = fmaf(a, kn.x, acc[ti].x);
                acc[ti].y = fmaf(a, kn.y, acc[ti].y);
                acc[ti].z = fmaf(a, kn.z, acc[ti].z);
                acc[ti].w = fmaf(a, kn.w, acc[ti].w);
            }
        }
#pragma unroll
        for (int ti = 0; ti < TT_; ti++)
            *(float4*)&sm[kg][ti][dq * 4] = acc[ti];
    }
    __syncthreads();

    // Cross-wave K reduction + coalesced float4 store (4 rows x 256)
    {
        const int ti = tid >> 6, dd = tid & 63;
        const float4 s0 = *(const float4*)&sm[0][ti][dd * 4];
        const float4 s1 = *(const float4*)&sm[1][ti][dd * 4];
        const float4 s2 = *(const float4*)&sm[2][ti][dd * 4];
        const float4 s3 = *(const float4*)&sm[3][ti][dd * 4];
        float4 o;
        o.x = s0.x + s1.x + s2.x + s3.x;
        o.y = s0.y + s1.y + s2.y + s3.y;
        o.z = s0.z + s1.z + s2.z + s3.z;
        o.w = s0.w + s1.w + s2.w + s3.w;
        *(float4*)&out[(b * T_ + t0 + ti) * DK_ + dd * 4] = o;
    }
}

// ---------------------------------------------------------------------------
extern "C" void kernel_launch(void* const* d_in, const int* in_sizes, int n_in,
                              void* d_out, int out_size, void* d_ws,
                              size_t ws_size, hipStream_t stream) {
    (void)in_sizes; (void)n_in; (void)d_ws; (void)ws_size; (void)out_size;
    const float* knw = (const float*)d_in[0];  // [B,K,DK]
    const float* enc = (const float*)d_in[1];  // [B,T,DE]
    const float* W1  = (const float*)d_in[2];  // [DE,U]
    const float* b1  = (const float*)d_in[3];  // [U]
    const float* W2  = (const float*)d_in[4];  // [DK,U]
    const float* b2  = (const float*)d_in[5];  // [U]
    const float* V   = (const float*)d_in[6];  // [U,1]
    // d_in[7] = bV: constant over K, cancels in softmax -> unused.
    float* out = (float*)d_out;

    gemm_both<<<384, 256, 0, stream>>>(enc, W1, b1, knw, W2, b2);
    attn_ctx<<<B_ * (T_ / TT_), 256, 0, stream>>>(knw, V, out);
}